// Round 6
// baseline (205.787 us; speedup 1.0000x reference)
//
#include <hip/hip_runtime.h>
#include <hip/hip_bf16.h>

// Problem constants (from reference)
#define N_COARSE 40962
#define N_NEW    122880
#define M_TOTAL  163842            // N_COARSE + N_NEW
#define CIN      256
#define COUT     256

#define BMP   128                               // rows per tile (4 Mgroups x 32)
#define TILES ((M_TOTAL + BMP - 1) / BMP)       // 1281
#define GRID  256                               // persistent, 1 block/CU

#define XB_BYTES ((size_t)N_COARSE * CIN * 2)   // 20,972,544
#define XCH      (N_COARSE * CIN / 8)           // x-chunks of 8 floats

typedef __bf16 bf16x8 __attribute__((ext_vector_type(8)));
typedef float  f32x4  __attribute__((ext_vector_type(4)));

static __device__ __forceinline__ unsigned short f2bf(float f) {
    unsigned int u = __builtin_bit_cast(unsigned int, f);
    u += 0x7FFFu + ((u >> 16) & 1u);   // round-to-nearest-even
    return (unsigned short)(u >> 16);
}

// average two int4-packed bf16x8 values -> bf16x8
static __device__ __forceinline__ bf16x8 bfavg(int4 a, int4 b) {
    const unsigned int* au = (const unsigned int*)&a;
    const unsigned int* bu = (const unsigned int*)&b;
    union { unsigned short h[8]; bf16x8 v; } r;
#pragma unroll
    for (int e = 0; e < 4; ++e) {
        const float alo = __builtin_bit_cast(float, au[e] << 16);
        const float ahi = __builtin_bit_cast(float, au[e] & 0xFFFF0000u);
        const float blo = __builtin_bit_cast(float, bu[e] << 16);
        const float bhi = __builtin_bit_cast(float, bu[e] & 0xFFFF0000u);
        r.h[2 * e]     = f2bf((alo + blo) * 0.5f);
        r.h[2 * e + 1] = f2bf((ahi + bhi) * 0.5f);
    }
    return r.v;
}

// ---------------------------------------------------------------------------
// x fp32 -> xb bf16 (21 MB in d_ws). Fully coalesced.
// ---------------------------------------------------------------------------
__global__ __launch_bounds__(256) void convx_kernel(
    const float* __restrict__ x, unsigned short* __restrict__ xb)
{
    const int k = blockIdx.x * 256 + threadIdx.x;
    if (k >= XCH) return;
    const int off = k * 8;
    float4 v0 = *(const float4*)(x + off);
    float4 v1 = *(const float4*)(x + off + 4);
    union { unsigned short h[8]; int4 v; } p;
    p.h[0] = f2bf(v0.x); p.h[1] = f2bf(v0.y); p.h[2] = f2bf(v0.z); p.h[3] = f2bf(v0.w);
    p.h[4] = f2bf(v1.x); p.h[5] = f2bf(v1.y); p.h[6] = f2bf(v1.z); p.h[7] = f2bf(v1.w);
    *(int4*)(xb + off) = p.v;
}

// ---------------------------------------------------------------------------
// Persistent fused GEMM. W (bf16, swizzled) resident in 128 KB LDS, staged
// once per block (the ONLY barrier). Grid-stride over 128-row tiles:
// A gathered direct-to-register (uniform p0/p1 path; coarse rows p0=p1=self),
// depth-2 load pipeline, MFMA vs ds_read_b128 W fragments (2-way = free),
// direct 64B-line stores (swapped-operand layout: 16 rows x 64B per instr).
// 16 waves (4 Mgroups x 4 Nquarters), VGPR target <=128.
// ---------------------------------------------------------------------------
__global__ __launch_bounds__(1024, 1) void gemm_persist_kernel(
    const unsigned short* __restrict__ xb,   // [N_COARSE][CIN] bf16
    const int*   __restrict__ idx,           // [N_NEW][2]
    const float* __restrict__ W,             // [COUT][CIN] fp32
    const float* __restrict__ bias,          // [COUT]
    float*       __restrict__ out)           // [M_TOTAL][COUT]
{
    __shared__ __align__(16) unsigned short Wl[COUT * CIN];  // 128 KB

    const int t    = threadIdx.x;
    const int lane = t & 63;
    const int wid  = t >> 6;       // 0..15
    const int mg   = wid >> 2;     // 0..3  M-group (32 rows)
    const int wcc  = wid & 3;      // 0..3  N-quarter (64 cols)
    const char* xbc = (const char*)xb;

    // ---- stage W once: fp32 -> bf16, XOR-swizzled rows ----
#pragma unroll
    for (int it = 0; it < (COUT * CIN / 8) / 1024; ++it) {
        const int i    = it * 1024 + t;         // chunk of 8 elems
        const int wrow = i >> 5;                // W row (out col)
        const int wbyt = (i & 31) * 16;         // byte col in bf16 row
        float4 v0 = *(const float4*)(W + i * 8);
        float4 v1 = *(const float4*)(W + i * 8 + 4);
        union { unsigned short h[8]; int4 v; } p;
        p.h[0] = f2bf(v0.x); p.h[1] = f2bf(v0.y); p.h[2] = f2bf(v0.z); p.h[3] = f2bf(v0.w);
        p.h[4] = f2bf(v1.x); p.h[5] = f2bf(v1.y); p.h[6] = f2bf(v1.z); p.h[7] = f2bf(v1.w);
        *(int4*)((char*)Wl + wrow * 512 + (wbyt ^ ((wrow & 7) << 4))) = p.v;
    }
    __syncthreads();   // the only barrier in the kernel

    const int l15 = lane & 15;
    const int lc  = (lane >> 4) << 4;   // 16B chunk within 64B

    for (int tile = blockIdx.x; tile < TILES; tile += GRID) {
        const int m0 = tile * BMP + mg * 32;

        // per-fragment parent byte-offsets into xb (32-bit)
        unsigned oA0, oB0, oA1, oB1;
#pragma unroll
        for (int i = 0; i < 2; ++i) {
            const int gr = m0 + i * 16 + l15;
            int p0, p1;
            if (gr >= M_TOTAL)      { p0 = 0; p1 = 0; }
            else if (gr >= N_COARSE) {
                const int2 pp = *(const int2*)(idx + 2 * (size_t)(gr - N_COARSE));
                p0 = pp.x; p1 = pp.y;
            } else                  { p0 = gr; p1 = gr; }
            const unsigned o0 = (unsigned)p0 * 512u + lc;
            const unsigned o1 = (unsigned)p1 * 512u + lc;
            if (i == 0) { oA0 = o0; oB0 = o1; } else { oA1 = o0; oB1 = o1; }
        }

        f32x4 acc[4][2];
#pragma unroll
        for (int j = 0; j < 4; ++j)
#pragma unroll
            for (int i = 0; i < 2; ++i)
                acc[j][i] = (f32x4){0.f, 0.f, 0.f, 0.f};

        // depth-2 pipeline on the gather loads
        int4 ra0 = *(const int4*)(xbc + oA0);
        int4 rb0 = *(const int4*)(xbc + oB0);
        int4 ra1 = *(const int4*)(xbc + oA1);
        int4 rb1 = *(const int4*)(xbc + oB1);

#pragma unroll
        for (int ks = 0; ks < 8; ++ks) {
            int4 na0, nb0, na1, nb1;
            if (ks < 7) {
                na0 = *(const int4*)(xbc + oA0 + (ks + 1) * 64);
                nb0 = *(const int4*)(xbc + oB0 + (ks + 1) * 64);
                na1 = *(const int4*)(xbc + oA1 + (ks + 1) * 64);
                nb1 = *(const int4*)(xbc + oB1 + (ks + 1) * 64);
            }
            const bf16x8 af0 = bfavg(ra0, rb0);
            const bf16x8 af1 = bfavg(ra1, rb1);

            const int wbyt = ks * 64 + lc;
            bf16x8 wf[4];
#pragma unroll
            for (int jj = 0; jj < 4; ++jj) {
                const int wr_ = wcc * 64 + jj * 16 + l15;
                wf[jj] = *(const bf16x8*)((const char*)Wl + wr_ * 512 +
                                          (wbyt ^ ((wr_ & 7) << 4)));
            }
#pragma unroll
            for (int jj = 0; jj < 4; ++jj) {
                acc[jj][0] = __builtin_amdgcn_mfma_f32_16x16x32_bf16(
                    wf[jj], af0, acc[jj][0], 0, 0, 0);
                acc[jj][1] = __builtin_amdgcn_mfma_f32_16x16x32_bf16(
                    wf[jj], af1, acc[jj][1], 0, 0, 0);
            }
            ra0 = na0; rb0 = nb0; ra1 = na1; rb1 = nb1;
        }

        // ---- epilogue: bias + direct 64B-line stores ----
        // lane's acc[j][i]: row = m0+i*16+l15, cols = wcc*64 + j*16 + (lane>>4)*4 +{0..3}
        const int nb4 = wcc * 64 + ((lane >> 4) << 2);
        f32x4 bv[4];
#pragma unroll
        for (int j = 0; j < 4; ++j)
            bv[j] = __builtin_bit_cast(f32x4, *(const float4*)(bias + nb4 + j * 16));
#pragma unroll
        for (int i = 0; i < 2; ++i) {
            const int gr = m0 + i * 16 + l15;
            if (gr < M_TOTAL) {
                char* orow = (char*)out + (size_t)gr * 1024 + wcc * 256 + lc;
#pragma unroll
                for (int j = 0; j < 4; ++j)
                    *(f32x4*)(orow + j * 64) = acc[j][i] + bv[j];
            }
        }
    }
}

// ---------------------------------------------------------------------------
// Fallback (only if ws too small): round-1 fused kernel, known-correct.
// ---------------------------------------------------------------------------
union Pk8 { unsigned short h[8]; int4 v; };

__global__ __launch_bounds__(256, 2) void unpool_linear_fused(
    const float* __restrict__ x, const int* __restrict__ idx,
    const float* __restrict__ W, const float* __restrict__ bias,
    float* __restrict__ out)
{
    __shared__ __align__(16) unsigned short As[128 * 64];
    __shared__ __align__(16) unsigned short Bs[128 * 64];
    const int m0 = blockIdx.x * 128;
    const int n0 = blockIdx.y * 128;
    const int t = threadIdx.x, lane = t & 63, wid = t >> 6;
    const int wr = wid >> 1, wc = wid & 1;
    f32x4 acc[4][4];
#pragma unroll
    for (int i = 0; i < 4; ++i)
#pragma unroll
        for (int j = 0; j < 4; ++j) acc[i][j] = (f32x4){0.f,0.f,0.f,0.f};
    for (int k0 = 0; k0 < CIN; k0 += 64) {
#pragma unroll
        for (int i = 0; i < 4; ++i) {
            const int chunk = t + i * 256, r = chunk >> 3, c8 = chunk & 7;
            const int kcol = k0 + c8 * 8;
            const int sidx = (r * 64 + c8 * 8) ^ ((r & 7) << 3);
            float v[8];
            const int gr = m0 + r;
            if (gr < N_COARSE) {
                const float* src = x + (size_t)gr * CIN + kcol;
                float4 a0 = *(const float4*)(src), a1 = *(const float4*)(src + 4);
                v[0]=a0.x; v[1]=a0.y; v[2]=a0.z; v[3]=a0.w;
                v[4]=a1.x; v[5]=a1.y; v[6]=a1.z; v[7]=a1.w;
            } else if (gr < M_TOTAL) {
                const int j = gr - N_COARSE;
                const int p0 = idx[2*j], p1 = idx[2*j+1];
                const float* s0 = x + (size_t)p0 * CIN + kcol;
                const float* s1 = x + (size_t)p1 * CIN + kcol;
                float4 a0=*(const float4*)(s0), a1=*(const float4*)(s0+4);
                float4 b0=*(const float4*)(s1), b1=*(const float4*)(s1+4);
                v[0]=(a0.x+b0.x)*.5f; v[1]=(a0.y+b0.y)*.5f; v[2]=(a0.z+b0.z)*.5f; v[3]=(a0.w+b0.w)*.5f;
                v[4]=(a1.x+b1.x)*.5f; v[5]=(a1.y+b1.y)*.5f; v[6]=(a1.z+b1.z)*.5f; v[7]=(a1.w+b1.w)*.5f;
            } else {
#pragma unroll
                for (int q = 0; q < 8; ++q) v[q] = 0.f;
            }
            Pk8 pa;
#pragma unroll
            for (int q = 0; q < 8; ++q) pa.h[q] = f2bf(v[q]);
            *(int4*)&As[sidx] = pa.v;
            const float* ws = W + (size_t)(n0 + r) * CIN + kcol;
            float4 w0 = *(const float4*)(ws), w1 = *(const float4*)(ws + 4);
            Pk8 pb;
            pb.h[0]=f2bf(w0.x); pb.h[1]=f2bf(w0.y); pb.h[2]=f2bf(w0.z); pb.h[3]=f2bf(w0.w);
            pb.h[4]=f2bf(w1.x); pb.h[5]=f2bf(w1.y); pb.h[6]=f2bf(w1.z); pb.h[7]=f2bf(w1.w);
            *(int4*)&Bs[sidx] = pb.v;
        }
        __syncthreads();
#pragma unroll
        for (int kk = 0; kk < 64; kk += 32) {
            const int kcol = kk + 8 * (lane >> 4);
            bf16x8 af[4], bfv[4];
#pragma unroll
            for (int i = 0; i < 4; ++i) {
                const int r = wr * 64 + i * 16 + (lane & 15);
                af[i] = __builtin_bit_cast(bf16x8, *(const int4*)&As[(r*64+kcol) ^ ((r&7)<<3)]);
            }
#pragma unroll
            for (int j = 0; j < 4; ++j) {
                const int r = wc * 64 + j * 16 + (lane & 15);
                bfv[j] = __builtin_bit_cast(bf16x8, *(const int4*)&Bs[(r*64+kcol) ^ ((r&7)<<3)]);
            }
#pragma unroll
            for (int i = 0; i < 4; ++i)
#pragma unroll
                for (int j = 0; j < 4; ++j)
                    acc[i][j] = __builtin_amdgcn_mfma_f32_16x16x32_bf16(af[i], bfv[j], acc[i][j], 0, 0, 0);
        }
        __syncthreads();
    }
    const int colbase = n0 + wc * 64 + (lane & 15);
    const int rowbase = m0 + wr * 64 + ((lane >> 4) << 2);
#pragma unroll
    for (int j = 0; j < 4; ++j) {
        const int col = colbase + j * 16;
        const float bv = bias[col];
#pragma unroll
        for (int i = 0; i < 4; ++i) {
            const int row = rowbase + i * 16;
#pragma unroll
            for (int r2 = 0; r2 < 4; ++r2) {
                const int rr = row + r2;
                if (rr < M_TOTAL) out[(size_t)rr * COUT + col] = acc[i][j][r2] + bv;
            }
        }
    }
}

extern "C" void kernel_launch(void* const* d_in, const int* in_sizes, int n_in,
                              void* d_out, int out_size, void* d_ws, size_t ws_size,
                              hipStream_t stream) {
    const float* x    = (const float*)d_in[0];
    const int*   idx  = (const int*)d_in[1];
    const float* W    = (const float*)d_in[2];
    const float* bias = (const float*)d_in[3];
    float* out = (float*)d_out;

    if (ws_size >= XB_BYTES) {
        unsigned short* xb = (unsigned short*)d_ws;
        convx_kernel<<<(XCH + 255) / 256, 256, 0, stream>>>(x, xb);
        gemm_persist_kernel<<<GRID, 1024, 0, stream>>>(xb, idx, W, bias, out);
    } else {
        dim3 grid((M_TOTAL + 127) / 128, COUT / 128);
        unpool_linear_fused<<<grid, 256, 0, stream>>>(x, idx, W, bias, out);
    }
}

// Round 7
// 75.247 us; speedup vs baseline: 2.7348x; 2.7348x over previous
//
#include <hip/hip_runtime.h>
#include <hip/hip_bf16.h>

// Problem constants (from reference)
#define N_COARSE 40962
#define N_NEW    122880
#define M_TOTAL  163842            // N_COARSE + N_NEW
#define CIN      256
#define COUT     256

#define BM    64
#define MT    ((M_TOTAL + BM - 1) / BM)     // 2561

#define XB_BYTES ((size_t)N_COARSE * CIN * 2)          // 20,972,544
#define WB_OFF   ((XB_BYTES + 255) & ~(size_t)255)
#define WB_BYTES ((size_t)COUT * CIN * 2)              // 131,072
#define WS_NEED  (WB_OFF + WB_BYTES)

#define XCH   (N_COARSE * CIN / 8)          // 1,310,784 x-chunks of 8 floats
#define WCH   (COUT * CIN / 8)              // 8,192 W-chunks
#define CVT_T (XCH + WCH)

typedef __bf16 bf16x8 __attribute__((ext_vector_type(8)));
typedef float  f32x4  __attribute__((ext_vector_type(4)));

static __device__ __forceinline__ unsigned short f2bf(float f) {
    unsigned int u = __builtin_bit_cast(unsigned int, f);
    u += 0x7FFFu + ((u >> 16) & 1u);   // round-to-nearest-even
    return (unsigned short)(u >> 16);
}

// ---------------------------------------------------------------------------
// Convert x -> xb bf16 (21 MB, linear) and W -> wb2 bf16 in MFMA-FRAGMENT
// order: chunk o = ((q*4+f)*8+ks)*64 + lane holds
// W[q*64+f*16+(lane&15)][ks*32+(lane>>4)*8 .. +8], so a wave's fragment load
// in the GEMM is one fully-coalesced 1KB read.
// ---------------------------------------------------------------------------
__global__ __launch_bounds__(256) void conv_kernel(
    const float* __restrict__ x, const float* __restrict__ W,
    unsigned short* __restrict__ xb, unsigned short* __restrict__ wb2)
{
    const int k = blockIdx.x * 256 + threadIdx.x;
    if (k >= CVT_T) return;
    const float* src;
    unsigned short* dst;
    if (k < XCH) {
        src = x + (size_t)k * 8;
        dst = xb + (size_t)k * 8;
    } else {
        const int o  = k - XCH;          // 0..8191
        const int l  = o & 63;
        const int ks = (o >> 6) & 7;
        const int f  = (o >> 9) & 3;
        const int q  = (o >> 11) & 3;
        const int row = q * 64 + f * 16 + (l & 15);
        const int ke  = ks * 32 + ((l >> 4) << 3);
        src = W + (size_t)row * CIN + ke;
        dst = wb2 + (size_t)o * 8;
    }
    float4 v0 = *(const float4*)(src);
    float4 v1 = *(const float4*)(src + 4);
    union { unsigned short h[8]; int4 v; } p;
    p.h[0] = f2bf(v0.x); p.h[1] = f2bf(v0.y); p.h[2] = f2bf(v0.z); p.h[3] = f2bf(v0.w);
    p.h[4] = f2bf(v1.x); p.h[5] = f2bf(v1.y); p.h[6] = f2bf(v1.z); p.h[7] = f2bf(v1.w);
    *(int4*)dst = p.v;
}

// ---------------------------------------------------------------------------
// Fused GEMM over all 163842 rows. A-stage (one barrier): coarse rows copied,
// new rows gathered+averaged from the L2/L3-resident 21 MB xb into swizzled
// LDS. K-loop: ZERO barriers -- af via ds_read_b128, wf via coalesced 1KB
// global loads from the L2-resident fragment-ordered wb2; compiler free to
// software-pipeline. Swapped-operand MFMA + LDS-transpose epilogue
// (1KB-contiguous stores, no write amplification).
// LDS: As 32 KB only -> 3 blocks/CU at VGPR<=85 (24 waves/CU).
// ---------------------------------------------------------------------------
__global__ __launch_bounds__(512, 6) void fused_gemm_kernel(
    const unsigned short* __restrict__ xb,   // [N_COARSE][CIN] bf16
    const int*   __restrict__ idx,           // [N_NEW][2]
    const unsigned short* __restrict__ wb2,  // fragment-ordered bf16 W
    const float* __restrict__ bias,          // [COUT]
    float*       __restrict__ out)           // [M_TOTAL][COUT]
{
    __shared__ __align__(16) unsigned short As[BM * CIN];   // 32 KB (swizzled)

    const int brow = blockIdx.x * BM;
    const int t    = threadIdx.x;
    const int lane = t & 63;
    const int wid  = t >> 6;      // 0..7
    const int wrr  = wid >> 2;    // 0..1  (32-row half of A)
    const int wcc  = wid & 3;     // 0..3  (64-col quarter of out)

    // ---- A-stage: copy (coarse) or gather+avg (new), swizzled ds_write ----
    {
        const int r  = t >> 3;          // tile row 0..63 (8 threads/row)
        const int q  = t & 7;           // 32-col chunk (64B)
        const int gr = brow + r;
        char* arow = (char*)As + r * 512;
        const int swz = (r & 7) << 4;
        const int cb0 = q * 64;
        if (gr < N_COARSE || gr >= M_TOTAL) {
            const int sr = (gr < N_COARSE) ? gr : 0;   // pad rows: junk, unstored
            const char* s = (const char*)xb + (size_t)sr * 512 + cb0;
#pragma unroll
            for (int c = 0; c < 4; ++c)
                *(int4*)(arow + ((cb0 + c * 16) ^ swz)) = *(const int4*)(s + c * 16);
        } else {
            const int j  = gr - N_COARSE;
            const int p0 = idx[2 * j];
            const int p1 = idx[2 * j + 1];
            const char* s0 = (const char*)xb + (size_t)p0 * 512 + cb0;
            const char* s1 = (const char*)xb + (size_t)p1 * 512 + cb0;
#pragma unroll
            for (int c = 0; c < 4; ++c) {
                int4 a = *(const int4*)(s0 + c * 16);
                int4 b = *(const int4*)(s1 + c * 16);
                const unsigned int* au = (const unsigned int*)&a;
                const unsigned int* bu = (const unsigned int*)&b;
                union { unsigned short h[8]; int4 v; } p;
#pragma unroll
                for (int e = 0; e < 4; ++e) {
                    const float alo = __builtin_bit_cast(float, au[e] << 16);
                    const float ahi = __builtin_bit_cast(float, au[e] & 0xFFFF0000u);
                    const float blo = __builtin_bit_cast(float, bu[e] << 16);
                    const float bhi = __builtin_bit_cast(float, bu[e] & 0xFFFF0000u);
                    p.h[2 * e]     = f2bf((alo + blo) * 0.5f);
                    p.h[2 * e + 1] = f2bf((ahi + bhi) * 0.5f);
                }
                *(int4*)(arow + ((cb0 + c * 16) ^ swz)) = p.v;
            }
        }
    }

    f32x4 acc[4][2];   // acc[j][i]: j = N quadrant, i = M fragment
#pragma unroll
    for (int j = 0; j < 4; ++j)
#pragma unroll
        for (int i = 0; i < 2; ++i)
            acc[j][i] = (f32x4){0.f, 0.f, 0.f, 0.f};

    __syncthreads();   // As ready -- the only barrier before the epilogue

    // per-lane W fragment base: wb2 + wcc*32768 + jj*8192 + ks*1024 + lane*16
    const char* wbase = (const char*)wb2 + wcc * 32768 + lane * 16;

    // ---- K-loop: 8 steps, no barriers, compiler-pipelined ----
#pragma unroll
    for (int ks = 0; ks < 8; ++ks) {
        bf16x8 af[2], wf[4];
        const int acb = ks * 64 + ((lane >> 4) << 4);
#pragma unroll
        for (int i = 0; i < 2; ++i) {
            const int ar = wrr * 32 + i * 16 + (lane & 15);
            af[i] = __builtin_bit_cast(bf16x8,
                *(const int4*)((const char*)As + ar * 512 + (acb ^ ((ar & 7) << 4))));
        }
#pragma unroll
        for (int jj = 0; jj < 4; ++jj)
            wf[jj] = *(const bf16x8*)(wbase + jj * 8192 + ks * 1024);

        // swapped operands: lane&15 -> M row, (lane>>4)*4+reg -> N col
#pragma unroll
        for (int jj = 0; jj < 4; ++jj) {
            acc[jj][0] = __builtin_amdgcn_mfma_f32_16x16x32_bf16(
                wf[jj], af[0], acc[jj][0], 0, 0, 0);
            acc[jj][1] = __builtin_amdgcn_mfma_f32_16x16x32_bf16(
                wf[jj], af[1], acc[jj][1], 0, 0, 0);
        }
    }

    // ---- bias (each lane owns 4 consecutive n) ----
    const int nb = wcc * 64 + ((lane >> 4) << 2);
#pragma unroll
    for (int j = 0; j < 4; ++j) {
        const f32x4 bv = __builtin_bit_cast(f32x4, *(const float4*)(bias + nb + j * 16));
#pragma unroll
        for (int i = 0; i < 2; ++i)
            acc[j][i] = acc[j][i] + bv;
    }

    // ---- epilogue: LDS transpose (reuse As as [32][256] f32), 1KB stores ----
    float* Af = (float*)As;
    for (int h = 0; h < 2; ++h) {
        __syncthreads();
        if (wrr == h) {
#pragma unroll
            for (int j = 0; j < 4; ++j)
#pragma unroll
                for (int i = 0; i < 2; ++i) {
                    const int r  = i * 16 + (lane & 15);                    // 0..31
                    const int cb = wcc * 256 + j * 64 + ((lane >> 4) << 4); // byte col
                    *(f32x4*)((char*)Af + r * 1024 + (cb ^ ((r & 7) << 4))) = acc[j][i];
                }
        }
        __syncthreads();
#pragma unroll
        for (int ri = 0; ri < 4; ++ri) {
            const int r = wid * 4 + ri;
            const f32x4 v = *(const f32x4*)((const char*)Af + r * 1024 +
                                            ((lane * 16) ^ ((r & 7) << 4)));
            const int gr = brow + h * 32 + r;
            if (gr < M_TOTAL)
                *(f32x4*)((char*)out + (size_t)gr * 1024 + lane * 16) = v;
        }
    }
}

// ---------------------------------------------------------------------------
// Fallback (only if ws too small): round-1 fused kernel, known-correct.
// ---------------------------------------------------------------------------
union Pk8 { unsigned short h[8]; int4 v; };

__global__ __launch_bounds__(256, 2) void unpool_linear_fused(
    const float* __restrict__ x, const int* __restrict__ idx,
    const float* __restrict__ W, const float* __restrict__ bias,
    float* __restrict__ out)
{
    __shared__ __align__(16) unsigned short As[128 * 64];
    __shared__ __align__(16) unsigned short Bs[128 * 64];
    const int m0 = blockIdx.x * 128;
    const int n0 = blockIdx.y * 128;
    const int t = threadIdx.x, lane = t & 63, wid = t >> 6;
    const int wr = wid >> 1, wc = wid & 1;
    f32x4 acc[4][4];
#pragma unroll
    for (int i = 0; i < 4; ++i)
#pragma unroll
        for (int j = 0; j < 4; ++j) acc[i][j] = (f32x4){0.f,0.f,0.f,0.f};
    for (int k0 = 0; k0 < CIN; k0 += 64) {
#pragma unroll
        for (int i = 0; i < 4; ++i) {
            const int chunk = t + i * 256, r = chunk >> 3, c8 = chunk & 7;
            const int kcol = k0 + c8 * 8;
            const int sidx = (r * 64 + c8 * 8) ^ ((r & 7) << 3);
            float v[8];
            const int gr = m0 + r;
            if (gr < N_COARSE) {
                const float* src = x + (size_t)gr * CIN + kcol;
                float4 a0 = *(const float4*)(src), a1 = *(const float4*)(src + 4);
                v[0]=a0.x; v[1]=a0.y; v[2]=a0.z; v[3]=a0.w;
                v[4]=a1.x; v[5]=a1.y; v[6]=a1.z; v[7]=a1.w;
            } else if (gr < M_TOTAL) {
                const int j = gr - N_COARSE;
                const int p0 = idx[2*j], p1 = idx[2*j+1];
                const float* s0 = x + (size_t)p0 * CIN + kcol;
                const float* s1 = x + (size_t)p1 * CIN + kcol;
                float4 a0=*(const float4*)(s0), a1=*(const float4*)(s0+4);
                float4 b0=*(const float4*)(s1), b1=*(const float4*)(s1+4);
                v[0]=(a0.x+b0.x)*.5f; v[1]=(a0.y+b0.y)*.5f; v[2]=(a0.z+b0.z)*.5f; v[3]=(a0.w+b0.w)*.5f;
                v[4]=(a1.x+b1.x)*.5f; v[5]=(a1.y+b1.y)*.5f; v[6]=(a1.z+b1.z)*.5f; v[7]=(a1.w+b1.w)*.5f;
            } else {
#pragma unroll
                for (int q = 0; q < 8; ++q) v[q] = 0.f;
            }
            Pk8 pa;
#pragma unroll
            for (int q = 0; q < 8; ++q) pa.h[q] = f2bf(v[q]);
            *(int4*)&As[sidx] = pa.v;
            const float* ws = W + (size_t)(n0 + r) * CIN + kcol;
            float4 w0 = *(const float4*)(ws), w1 = *(const float4*)(ws + 4);
            Pk8 pb;
            pb.h[0]=f2bf(w0.x); pb.h[1]=f2bf(w0.y); pb.h[2]=f2bf(w0.z); pb.h[3]=f2bf(w0.w);
            pb.h[4]=f2bf(w1.x); pb.h[5]=f2bf(w1.y); pb.h[6]=f2bf(w1.z); pb.h[7]=f2bf(w1.w);
            *(int4*)&Bs[sidx] = pb.v;
        }
        __syncthreads();
#pragma unroll
        for (int kk = 0; kk < 64; kk += 32) {
            const int kcol = kk + 8 * (lane >> 4);
            bf16x8 af[4], bfv[4];
#pragma unroll
            for (int i = 0; i < 4; ++i) {
                const int r = wr * 64 + i * 16 + (lane & 15);
                af[i] = __builtin_bit_cast(bf16x8, *(const int4*)&As[(r*64+kcol) ^ ((r&7)<<3)]);
            }
#pragma unroll
            for (int j = 0; j < 4; ++j) {
                const int r = wc * 64 + j * 16 + (lane & 15);
                bfv[j] = __builtin_bit_cast(bf16x8, *(const int4*)&Bs[(r*64+kcol) ^ ((r&7)<<3)]);
            }
#pragma unroll
            for (int i = 0; i < 4; ++i)
#pragma unroll
                for (int j = 0; j < 4; ++j)
                    acc[i][j] = __builtin_amdgcn_mfma_f32_16x16x32_bf16(af[i], bfv[j], acc[i][j], 0, 0, 0);
        }
        __syncthreads();
    }
    const int colbase = n0 + wc * 64 + (lane & 15);
    const int rowbase = m0 + wr * 64 + ((lane >> 4) << 2);
#pragma unroll
    for (int j = 0; j < 4; ++j) {
        const int col = colbase + j * 16;
        const float bv = bias[col];
#pragma unroll
        for (int i = 0; i < 4; ++i) {
            const int row = rowbase + i * 16;
#pragma unroll
            for (int r2 = 0; r2 < 4; ++r2) {
                const int rr = row + r2;
                if (rr < M_TOTAL) out[(size_t)rr * COUT + col] = acc[i][j][r2] + bv;
            }
        }
    }
}

extern "C" void kernel_launch(void* const* d_in, const int* in_sizes, int n_in,
                              void* d_out, int out_size, void* d_ws, size_t ws_size,
                              hipStream_t stream) {
    const float* x    = (const float*)d_in[0];
    const int*   idx  = (const int*)d_in[1];
    const float* W    = (const float*)d_in[2];
    const float* bias = (const float*)d_in[3];
    float* out = (float*)d_out;

    if (ws_size >= WS_NEED) {
        unsigned short* xb  = (unsigned short*)d_ws;
        unsigned short* wb2 = (unsigned short*)((char*)d_ws + WB_OFF);
        conv_kernel<<<(CVT_T + 255) / 256, 256, 0, stream>>>(x, W, xb, wb2);
        fused_gemm_kernel<<<MT, 512, 0, stream>>>(xb, idx, wb2, bias, out);
    } else {
        dim3 grid((M_TOTAL + 127) / 128, COUT / 128);
        unpool_linear_fused<<<grid, 256, 0, stream>>>(x, idx, W, bias, out);
    }
}